// Round 1
// baseline (1368.060 us; speedup 1.0000x reference)
//
#include <hip/hip_runtime.h>

#define TLEN 300
#define THETA 10.0f
#define REF_DECAY 0.36787944117144233f

// ---------------- eps table: eps[k] = (k/10) * exp(1 - k/10), k=0..99 ----------------
__global__ void eps_init_kernel(float* __restrict__ eps) {
  int k = threadIdx.x;
  if (k < 100) {
    float a = (float)k / 10.0f;
    eps[k] = a * expf(1.0f - a);
  }
}

// ---------------- 4x4 sum-pool on raw input, scale 1.1*theta/16 = 0.6875 ----------------
__global__ __launch_bounds__(256) void pool4_kernel(const float* __restrict__ in,
                                                    float* __restrict__ out) {
  int idx = blockIdx.x * 256 + threadIdx.x;
  const int total = 4 * 2 * 32 * 32 * TLEN;
  if (idx >= total) return;
  int t = idx % TLEN;
  int rest = idx / TLEN;
  int x = rest % 32; rest /= 32;
  int y = rest % 32; rest /= 32;
  int bc = rest;  // b*2+c, 0..7
  const float* base = in + ((long)(bc * 128 + y * 4) * 128 + x * 4) * TLEN + t;
  float s = 0.f;
#pragma unroll
  for (int dy = 0; dy < 4; ++dy)
#pragma unroll
    for (int dx = 0; dx < 4; ++dx)
      s += base[(dy * 128 + dx) * TLEN];
  out[idx] = s * 0.6875f;
}

// ---------------- PSP: exact truncated 100-tap FIR along t ----------------
// 4 rows per block (320 threads: 4 x 80 lanes, 75 active each -> 4 outputs/thread).
// Sliding register window; one aligned ds_read_b128 per 4 k-taps x 4 outputs.
__global__ __launch_bounds__(320) void psp_kernel(const float* __restrict__ x,
                                                  float* __restrict__ y,
                                                  const float* __restrict__ eps,
                                                  int rows) {
  __shared__ float xs[4][400];  // [row][99 zero-pad | 300 data | 1 pad]
  const int tid = threadIdx.x;
  const int row0 = blockIdx.x * 4;
  for (int i = tid; i < 1600; i += 320) {
    int r = i / 400, j = i - r * 400;
    int t = j - 99;
    float v = 0.f;
    if (t >= 0 && t < TLEN) v = x[(long)(row0 + r) * TLEN + t];
    xs[r][j] = v;
  }
  __syncthreads();
  const int r = tid / 80;
  const int l = tid - r * 80;
  if (l >= 75) return;
  const int t0 = 4 * l;
  const float* xr = &xs[r][99 + t0];
  float a0 = 0.f, a1 = 0.f, a2 = 0.f, a3 = 0.f;
  // p4 holds x[t0+1 .. t0+4] (aligned); n4 holds x[t0-kg-3 .. t0-kg]
  float4 p4 = *reinterpret_cast<const float4*>(xr + 1);
#pragma unroll
  for (int kg = 0; kg < 100; kg += 4) {
    const float4 e = *reinterpret_cast<const float4*>(eps + kg);
    const float4 n4 = *reinterpret_cast<const float4*>(xr - kg - 3);
    // acc[j] += eps[kg+dk] * x[t0 + j - kg - dk]
    a0 += e.x * n4.w;  a1 += e.x * p4.x;  a2 += e.x * p4.y;  a3 += e.x * p4.z;
    a0 += e.y * n4.z;  a1 += e.y * n4.w;  a2 += e.y * p4.x;  a3 += e.y * p4.y;
    a0 += e.z * n4.y;  a1 += e.z * n4.z;  a2 += e.z * n4.w;  a3 += e.z * p4.x;
    a0 += e.w * n4.x;  a1 += e.w * n4.y;  a2 += e.w * n4.z;  a3 += e.w * n4.w;
    p4 = n4;
  }
  float4 res; res.x = a0; res.y = a1; res.z = a2; res.w = a3;
  *reinterpret_cast<float4*>(y + (long)(row0 + r) * TLEN + t0) = res;
}

// ---------------- spike: sequential refractory scan per row, LDS-tiled ----------------
__global__ __launch_bounds__(256) void spike_kernel(const float* __restrict__ u,
                                                    float* __restrict__ s, int rows) {
  __shared__ float tile[256][33];
  const int tid = threadIdx.x;
  const int row0 = blockIdx.x * 256;
  const int myrow = row0 + tid;
  float ref = 0.f;
  for (int t0 = 0; t0 < TLEN; t0 += 32) {
    const int tw = min(32, TLEN - t0);
#pragma unroll
    for (int k = 0; k < 32; ++k) {
      int idx = k * 256 + tid;
      int rr = idx >> 5, cc = idx & 31;
      int grow = row0 + rr;
      if (cc < tw && grow < rows) tile[rr][cc] = u[(long)grow * TLEN + t0 + cc];
    }
    __syncthreads();
    if (myrow < rows) {
      for (int c = 0; c < tw; ++c) {
        float v = tile[tid][c] + ref - THETA;
        float sp = (v >= 0.f) ? 1.f : 0.f;
        tile[tid][c] = sp;
        ref = REF_DECAY * ref - 20.0f * sp;
      }
    }
    __syncthreads();
#pragma unroll
    for (int k = 0; k < 32; ++k) {
      int idx = k * 256 + tid;
      int rr = idx >> 5, cc = idx & 31;
      int grow = row0 + rr;
      if (cc < tw && grow < rows) s[(long)grow * TLEN + t0 + cc] = tile[rr][cc];
    }
    __syncthreads();
  }
}

// ---------------- conv1: 2->16 ch, 5x5, pad 2, on 32x32, per-t ----------------
// block = (t-chunk 32, y, b); LDS input tile [c2][dy5][x36][t32]; lanes: t-group fastest.
__global__ __launch_bounds__(256) void conv1_kernel(const float* __restrict__ in,
                                                    const float* __restrict__ w,
                                                    float* __restrict__ out) {
  __shared__ float xl[11520];
  const int tid = threadIdx.x;
  const int t0 = blockIdx.x * 32;
  const int y = blockIdx.y;
  const int b = blockIdx.z;
  for (int i = tid; i < 11520; i += 256) {
    int tt = i & 31;
    int rest = i >> 5;
    int xp = rest % 36; rest /= 36;
    int dy = rest % 5;
    int c = rest / 5;
    int yy = y + dy - 2, xx = xp - 2, t = t0 + tt;
    float v = 0.f;
    if (yy >= 0 && yy < 32 && xx >= 0 && xx < 32 && t < TLEN)
      v = in[((long)((b * 2 + c) * 32 + yy) * 32 + xx) * TLEN + t];
    xl[i] = v;
  }
  __syncthreads();
  const int tg = tid & 7;   // t-group (4 t's each)
  const int x = tid >> 3;   // 0..31
  float acc[16][4];
#pragma unroll
  for (int o = 0; o < 16; ++o) { acc[o][0] = acc[o][1] = acc[o][2] = acc[o][3] = 0.f; }
  for (int c = 0; c < 2; ++c)
#pragma unroll
    for (int dy = 0; dy < 5; ++dy)
#pragma unroll
      for (int kx = 0; kx < 5; ++kx) {
        const float4 xv = *reinterpret_cast<const float4*>(
            &xl[((c * 5 + dy) * 36 + x + kx) * 32 + tg * 4]);
        const float* wp = w + (c * 5 + dy) * 5 + kx;
#pragma unroll
        for (int o = 0; o < 16; ++o) {
          float wsc = wp[o * 50];
          acc[o][0] += wsc * xv.x; acc[o][1] += wsc * xv.y;
          acc[o][2] += wsc * xv.z; acc[o][3] += wsc * xv.w;
        }
      }
  const int t = t0 + tg * 4;
  if (t < TLEN) {
#pragma unroll
    for (int o = 0; o < 16; ++o) {
      float4 res; res.x = acc[o][0]; res.y = acc[o][1]; res.z = acc[o][2]; res.w = acc[o][3];
      *reinterpret_cast<float4*>(&out[((long)((b * 16 + o) * 32 + y) * 32 + x) * TLEN + t]) = res;
    }
  }
}

// ---------------- conv2: 16->32 ch, 3x3, pad 1, on 16x16, per-t ----------------
// block = (t-chunk 16, y, b); LDS [c16][dy3][x18][t16]; wave handles 8 o's.
__global__ __launch_bounds__(256) void conv2_kernel(const float* __restrict__ in,
                                                    const float* __restrict__ w,
                                                    float* __restrict__ out) {
  __shared__ float xl[13824];
  const int tid = threadIdx.x;
  const int t0 = blockIdx.x * 16;
  const int y = blockIdx.y;
  const int b = blockIdx.z;
  for (int i = tid; i < 13824; i += 256) {
    int tt = i & 15;
    int rest = i >> 4;
    int xp = rest % 18; rest /= 18;
    int dy = rest % 3;
    int c = rest / 3;
    int yy = y + dy - 1, xx = xp - 1, t = t0 + tt;
    float v = 0.f;
    if (yy >= 0 && yy < 16 && xx >= 0 && xx < 16 && t < TLEN)
      v = in[((long)((b * 16 + c) * 16 + yy) * 16 + xx) * TLEN + t];
    xl[i] = v;
  }
  __syncthreads();
  const int tg = tid & 3;          // t-group (4 t's)
  const int x = (tid >> 2) & 15;   // 0..15
  const int oh = tid >> 6;         // 0..3 (wave id): o = oh*8 + oo
  float acc[8][4];
#pragma unroll
  for (int o = 0; o < 8; ++o) { acc[o][0] = acc[o][1] = acc[o][2] = acc[o][3] = 0.f; }
  for (int c = 0; c < 16; ++c)
#pragma unroll
    for (int dy = 0; dy < 3; ++dy)
#pragma unroll
      for (int kx = 0; kx < 3; ++kx) {
        const float4 xv = *reinterpret_cast<const float4*>(
            &xl[((c * 3 + dy) * 18 + x + kx) * 16 + tg * 4]);
        const float* wp = w + (c * 3 + dy) * 3 + kx;
#pragma unroll
        for (int oo = 0; oo < 8; ++oo) {
          float wsc = wp[(oh * 8 + oo) * 144];
          acc[oo][0] += wsc * xv.x; acc[oo][1] += wsc * xv.y;
          acc[oo][2] += wsc * xv.z; acc[oo][3] += wsc * xv.w;
        }
      }
  const int t = t0 + tg * 4;
  if (t < TLEN) {
#pragma unroll
    for (int oo = 0; oo < 8; ++oo) {
      int o = oh * 8 + oo;
      float4 res; res.x = acc[oo][0]; res.y = acc[oo][1]; res.z = acc[oo][2]; res.w = acc[oo][3];
      *reinterpret_cast<float4*>(&out[((long)((b * 32 + o) * 16 + y) * 16 + x) * TLEN + t]) = res;
    }
  }
}

// ---------------- fused delay (per-channel lerp gather) + 2x2 pool, scale 2.75 ----------------
__global__ __launch_bounds__(256) void pool2_delay_kernel(const float* __restrict__ in,
                                                          const float* __restrict__ d,
                                                          float* __restrict__ out,
                                                          int C, int HO, int WO, int total) {
  int idx = blockIdx.x * 256 + threadIdx.x;
  if (idx >= total) return;
  int t = idx % TLEN;
  int rest = idx / TLEN;
  int x = rest % WO; rest /= WO;
  int y = rest % HO; rest /= HO;
  int c = rest % C;
  int b = rest / C;
  float dd = d[c];
  float src = (float)t - dd;
  float fi = floorf(src);
  int i0 = (int)fi;
  float wf = src - fi;
  const float* base = in + (((long)(b * C + c) * (2 * HO) + 2 * y) * (2 * WO) + 2 * x) * TLEN;
  long rs = (long)(2 * WO) * TLEN;
  bool ok0 = (i0 >= 0) && (i0 < TLEN);
  bool ok1 = (i0 + 1 >= 0) && (i0 + 1 < TLEN);
  int j0 = min(max(i0, 0), TLEN - 1);
  int j1 = min(max(i0 + 1, 0), TLEN - 1);
  float s0 = 0.f, s1 = 0.f;
#pragma unroll
  for (int dy = 0; dy < 2; ++dy)
#pragma unroll
    for (int dx = 0; dx < 2; ++dx) {
      const float* p = base + dy * rs + dx * TLEN;
      s0 += ok0 ? p[j0] : 0.f;
      s1 += ok1 ? p[j1] : 0.f;
    }
  out[idx] = (s0 * (1.f - wf) + s1 * wf) * 2.75f;
}

// ---------------- plain per-channel delay ----------------
__global__ __launch_bounds__(256) void delay_kernel(const float* __restrict__ in,
                                                    const float* __restrict__ d,
                                                    float* __restrict__ out,
                                                    int C, int S, int total) {
  int idx = blockIdx.x * 256 + threadIdx.x;
  if (idx >= total) return;
  int t = idx % TLEN;
  int rest = idx / TLEN;  // b*C*S + c*S + s
  int cs = rest % (C * S);
  int c = cs / S;
  float dd = d[c];
  float src = (float)t - dd;
  float fi = floorf(src);
  int i0 = (int)fi;
  float wf = src - fi;
  const float* base = in + (long)rest * TLEN;
  float v0 = (i0 >= 0 && i0 < TLEN) ? base[min(max(i0, 0), TLEN - 1)] : 0.f;
  float v1 = (i0 + 1 >= 0 && i0 + 1 < TLEN) ? base[min(max(i0 + 1, 0), TLEN - 1)] : 0.f;
  out[idx] = v0 * (1.f - wf) + v1 * wf;
}

// ---------------- fc1: [512,2048] x [4,2048,300] -> [4,512,300], tiled GEMM ----------------
__global__ __launch_bounds__(256) void fc1_kernel(const float* __restrict__ x,
                                                  const float* __restrict__ w,
                                                  float* __restrict__ out) {
  __shared__ float wl[32][68];
  __shared__ float xlb[32][68];
  const int tid = threadIdx.x;
  const int t0 = blockIdx.x * 64;
  const int o0 = blockIdx.y * 64;
  const int b = blockIdx.z;
  const int tx = tid & 15, ty = tid >> 4;
  float a[4][4];
#pragma unroll
  for (int i = 0; i < 4; ++i)
#pragma unroll
    for (int j = 0; j < 4; ++j) a[i][j] = 0.f;
  for (int kc = 0; kc < 2048; kc += 32) {
    __syncthreads();
    for (int i = tid; i < 2048; i += 256) {
      int ol = i >> 5, kl = i & 31;
      wl[kl][ol] = w[(long)(o0 + ol) * 2048 + kc + kl];
    }
    for (int i = tid; i < 2048; i += 256) {
      int kl = i >> 6, tl = i & 63;
      int t = t0 + tl;
      xlb[kl][tl] = (t < TLEN) ? x[((long)b * 2048 + kc + kl) * TLEN + t] : 0.f;
    }
    __syncthreads();
#pragma unroll
    for (int kk = 0; kk < 32; ++kk) {
      const float4 wv = *reinterpret_cast<const float4*>(&wl[kk][ty * 4]);
      const float4 xv = *reinterpret_cast<const float4*>(&xlb[kk][tx * 4]);
      float wa[4] = {wv.x, wv.y, wv.z, wv.w};
      float xa[4] = {xv.x, xv.y, xv.z, xv.w};
#pragma unroll
      for (int i = 0; i < 4; ++i)
#pragma unroll
        for (int j = 0; j < 4; ++j) a[i][j] += wa[i] * xa[j];
    }
  }
  const int t = t0 + tx * 4;
  if (t < TLEN) {
#pragma unroll
    for (int i = 0; i < 4; ++i) {
      float4 res; res.x = a[i][0]; res.y = a[i][1]; res.z = a[i][2]; res.w = a[i][3];
      *reinterpret_cast<float4*>(&out[((long)b * 512 + o0 + ty * 4 + i) * TLEN + t]) = res;
    }
  }
}

// ---------------- fc2: [11,512] x [4,512,300] -> [4,11,300] ----------------
__global__ __launch_bounds__(320) void fc2_kernel(const float* __restrict__ x,
                                                  const float* __restrict__ w,
                                                  float* __restrict__ out) {
  int blk = blockIdx.x;
  int b = blk / 11, o = blk % 11;
  int t = threadIdx.x;
  if (t >= TLEN) return;
  const float* xr = x + (long)b * 512 * TLEN + t;
  const float* wr = w + o * 512;
  float acc = 0.f;
#pragma unroll 8
  for (int i = 0; i < 512; ++i) acc += wr[i] * xr[(long)i * TLEN];
  out[((long)b * 11 + o) * TLEN + t] = acc;
}

extern "C" void kernel_launch(void* const* d_in, const int* in_sizes, int n_in,
                              void* d_out, int out_size, void* d_ws, size_t ws_size,
                              hipStream_t stream) {
  const float* input = (const float*)d_in[0];   // [4,2,128,128,300]
  const float* w1    = (const float*)d_in[1];   // [16,2,5,5]
  const float* w2    = (const float*)d_in[2];   // [32,16,3,3]
  const float* wfc1  = (const float*)d_in[3];   // [512,2048]
  const float* wfc2  = (const float*)d_in[4];   // [11,512]
  const float* d1    = (const float*)d_in[5];   // [16]
  const float* d2    = (const float*)d_in[6];   // [32]
  const float* d3    = (const float*)d_in[7];   // [512]

  float* ws   = (float*)d_ws;
  float* big0 = ws;                    // 19,660,800 floats  [4,16,32,32,300]
  float* medA = big0 + 19660800;       //  4,915,200 floats
  float* medB = medA + 4915200;        //  4,915,200 floats
  float* fcA  = medB + 4915200;        //    614,400 floats
  float* fcB  = fcA + 614400;          //    614,400 floats
  float* eps  = fcB + 614400;          //        128 floats

  hipLaunchKernelGGL(eps_init_kernel, dim3(1), dim3(128), 0, stream, eps);

  // L1: spike(psp(pool4(input)))
  hipLaunchKernelGGL(pool4_kernel, dim3(9600), dim3(256), 0, stream, input, medA);
  hipLaunchKernelGGL(psp_kernel, dim3(2048), dim3(320), 0, stream, medA, medB, eps, 8192);
  hipLaunchKernelGGL(spike_kernel, dim3(32), dim3(256), 0, stream, medB, medB, 8192);
  // L2: spike(conv1(psp(S0)))
  hipLaunchKernelGGL(psp_kernel, dim3(2048), dim3(320), 0, stream, medB, medA, eps, 8192);
  hipLaunchKernelGGL(conv1_kernel, dim3(10, 32, 4), dim3(256), 0, stream, medA, w1, big0);
  hipLaunchKernelGGL(spike_kernel, dim3(256), dim3(256), 0, stream, big0, big0, 65536);
  // L3: spike(psp(pool2(delay1(S1))))
  hipLaunchKernelGGL(pool2_delay_kernel, dim3(19200), dim3(256), 0, stream,
                     big0, d1, medA, 16, 16, 16, 4915200);
  hipLaunchKernelGGL(psp_kernel, dim3(4096), dim3(320), 0, stream, medA, medB, eps, 16384);
  hipLaunchKernelGGL(spike_kernel, dim3(64), dim3(256), 0, stream, medB, medB, 16384);
  // L4: spike(conv2(psp(S2)))
  hipLaunchKernelGGL(psp_kernel, dim3(4096), dim3(320), 0, stream, medB, medA, eps, 16384);
  hipLaunchKernelGGL(conv2_kernel, dim3(19, 16, 4), dim3(256), 0, stream, medA, w2, big0);
  hipLaunchKernelGGL(spike_kernel, dim3(128), dim3(256), 0, stream, big0, big0, 32768);
  // L5: spike(psp(pool2(delay2(S3))))
  hipLaunchKernelGGL(pool2_delay_kernel, dim3(9600), dim3(256), 0, stream,
                     big0, d2, medA, 32, 8, 8, 2457600);
  hipLaunchKernelGGL(psp_kernel, dim3(2048), dim3(320), 0, stream, medA, medB, eps, 8192);
  hipLaunchKernelGGL(spike_kernel, dim3(32), dim3(256), 0, stream, medB, medB, 8192);
  // L6: spike(fc1(psp(S4)))
  hipLaunchKernelGGL(psp_kernel, dim3(2048), dim3(320), 0, stream, medB, medA, eps, 8192);
  hipLaunchKernelGGL(fc1_kernel, dim3(5, 8, 4), dim3(256), 0, stream, medA, wfc1, fcA);
  hipLaunchKernelGGL(spike_kernel, dim3(8), dim3(256), 0, stream, fcA, fcA, 2048);
  // L7: spike(fc2(psp(delay3(S5)))) -> d_out
  hipLaunchKernelGGL(delay_kernel, dim3(2400), dim3(256), 0, stream, fcA, d3, fcB, 512, 1, 614400);
  hipLaunchKernelGGL(psp_kernel, dim3(512), dim3(320), 0, stream, fcB, fcA, eps, 2048);
  hipLaunchKernelGGL(fc2_kernel, dim3(44), dim3(320), 0, stream, fcA, wfc2, fcB);
  hipLaunchKernelGGL(spike_kernel, dim3(1), dim3(256), 0, stream, fcB, (float*)d_out, 44);
}

// Round 2
// 645.080 us; speedup vs baseline: 2.1208x; 2.1208x over previous
//
#include <hip/hip_runtime.h>

#define TLEN 300
#define THETA 10.0f
#define REF_DECAY 0.36787944117144233f

// ---------------- eps table: eps[k] = (k/10) * exp(1 - k/10), k=0..99 ----------------
__global__ void eps_init_kernel(float* __restrict__ eps) {
  int k = threadIdx.x;
  if (k < 100) {
    float a = (float)k / 10.0f;
    eps[k] = a * expf(1.0f - a);
  }
}

// ---------------- 4x4 sum-pool on raw input (float4 over t), scale 0.6875 ----------------
__global__ __launch_bounds__(256) void pool4_kernel(const float* __restrict__ in,
                                                    float* __restrict__ out) {
  int idx = blockIdx.x * 256 + threadIdx.x;  // quad index
  if (idx >= 153600) return;
  int tq = idx % 75;
  int rest = idx / 75;
  int x = rest & 31; rest >>= 5;
  int y = rest & 31; rest >>= 5;  // rest = bc (0..7)
  const float* base = in + ((long)(rest * 128 + y * 4) * 128 + x * 4) * TLEN + tq * 4;
  float4 s = {0.f, 0.f, 0.f, 0.f};
#pragma unroll
  for (int dy = 0; dy < 4; ++dy)
#pragma unroll
    for (int dx = 0; dx < 4; ++dx) {
      float4 v = *reinterpret_cast<const float4*>(base + (dy * 128 + dx) * TLEN);
      s.x += v.x; s.y += v.y; s.z += v.z; s.w += v.w;
    }
  s.x *= 0.6875f; s.y *= 0.6875f; s.z *= 0.6875f; s.w *= 0.6875f;
  *reinterpret_cast<float4*>(out + ((long)(rest * 32 + y) * 32 + x) * TLEN + tq * 4) = s;
}

// ---------------- PSP: exact truncated 100-tap FIR along t (4 rows/block) ----------------
__global__ __launch_bounds__(320) void psp_kernel(const float* __restrict__ x,
                                                  float* __restrict__ y,
                                                  const float* __restrict__ eps,
                                                  int rows) {
  __shared__ float xs[4][400];  // [row][99 zero-pad | 300 data | 1 pad]
  const int tid = threadIdx.x;
  const int row0 = blockIdx.x * 4;
  for (int i = tid; i < 1600; i += 320) {
    int r = i / 400, j = i - r * 400;
    int t = j - 99;
    float v = 0.f;
    if (t >= 0 && t < TLEN) v = x[(long)(row0 + r) * TLEN + t];
    xs[r][j] = v;
  }
  __syncthreads();
  const int r = tid / 80;
  const int l = tid - r * 80;
  if (l >= 75) return;
  const int t0 = 4 * l;
  const float* xr = &xs[r][99 + t0];
  float a0 = 0.f, a1 = 0.f, a2 = 0.f, a3 = 0.f;
  float4 p4 = *reinterpret_cast<const float4*>(xr + 1);
#pragma unroll
  for (int kg = 0; kg < 100; kg += 4) {
    const float4 e = *reinterpret_cast<const float4*>(eps + kg);
    const float4 n4 = *reinterpret_cast<const float4*>(xr - kg - 3);
    a0 += e.x * n4.w;  a1 += e.x * p4.x;  a2 += e.x * p4.y;  a3 += e.x * p4.z;
    a0 += e.y * n4.z;  a1 += e.y * n4.w;  a2 += e.y * p4.x;  a3 += e.y * p4.y;
    a0 += e.z * n4.y;  a1 += e.z * n4.z;  a2 += e.z * n4.w;  a3 += e.z * p4.x;
    a0 += e.w * n4.x;  a1 += e.w * n4.y;  a2 += e.w * n4.z;  a3 += e.w * n4.w;
    p4 = n4;
  }
  float4 res; res.x = a0; res.y = a1; res.z = a2; res.w = a3;
  *reinterpret_cast<float4*>(y + (long)(row0 + r) * TLEN + t0) = res;
}

// ---------------- PSP + fused spike scan (for layers whose psp feeds spike directly) ----------------
__global__ __launch_bounds__(320) void psp_spike_kernel(const float* __restrict__ x,
                                                        float* __restrict__ y,
                                                        const float* __restrict__ eps,
                                                        int rows) {
  __shared__ float xs[4][400];
  const int tid = threadIdx.x;
  const int row0 = blockIdx.x * 4;
  for (int i = tid; i < 1600; i += 320) {
    int r = i / 400, j = i - r * 400;
    int t = j - 99;
    float v = 0.f;
    if (t >= 0 && t < TLEN) v = x[(long)(row0 + r) * TLEN + t];
    xs[r][j] = v;
  }
  __syncthreads();
  const int r = tid / 80;
  const int l = tid - r * 80;
  const int t0 = 4 * l;
  float a0 = 0.f, a1 = 0.f, a2 = 0.f, a3 = 0.f;
  if (l < 75) {
    const float* xr = &xs[r][99 + t0];
    float4 p4 = *reinterpret_cast<const float4*>(xr + 1);
#pragma unroll
    for (int kg = 0; kg < 100; kg += 4) {
      const float4 e = *reinterpret_cast<const float4*>(eps + kg);
      const float4 n4 = *reinterpret_cast<const float4*>(xr - kg - 3);
      a0 += e.x * n4.w;  a1 += e.x * p4.x;  a2 += e.x * p4.y;  a3 += e.x * p4.z;
      a0 += e.y * n4.z;  a1 += e.y * n4.w;  a2 += e.y * p4.x;  a3 += e.y * p4.y;
      a0 += e.z * n4.y;  a1 += e.z * n4.z;  a2 += e.z * n4.w;  a3 += e.z * p4.x;
      a0 += e.w * n4.x;  a1 += e.w * n4.y;  a2 += e.w * n4.z;  a3 += e.w * n4.w;
      p4 = n4;
    }
  }
  __syncthreads();
  if (l < 75) {
    xs[r][99 + t0] = a0; xs[r][100 + t0] = a1; xs[r][101 + t0] = a2; xs[r][102 + t0] = a3;
  }
  __syncthreads();
  if (l == 0) {  // one scan lane per wave (tid 0,80,160,240)
    float ref = 0.f;
#pragma unroll 4
    for (int c = 0; c < TLEN; ++c) {
      float v = xs[r][99 + c] + ref - THETA;
      float sp = (v >= 0.f) ? 1.f : 0.f;
      xs[r][99 + c] = sp;
      ref = REF_DECAY * ref - 20.0f * sp;
    }
  }
  __syncthreads();
  if (l < 75) {
    float4 res;
    res.x = xs[r][99 + t0]; res.y = xs[r][100 + t0];
    res.z = xs[r][101 + t0]; res.w = xs[r][102 + t0];
    *reinterpret_cast<float4*>(y + (long)(row0 + r) * TLEN + t0) = res;
  }
}

// ---------------- PSP with fused per-channel delay on the input (layer 7) ----------------
__global__ __launch_bounds__(320) void psp_delay_kernel(const float* __restrict__ x,
                                                        float* __restrict__ y,
                                                        const float* __restrict__ eps,
                                                        const float* __restrict__ d,
                                                        int rows) {
  __shared__ float xs[4][400];
  const int tid = threadIdx.x;
  const int row0 = blockIdx.x * 4;
  for (int i = tid; i < 1600; i += 320) {
    int r = i / 400, j = i - r * 400;
    int row = row0 + r;
    float dd = d[row & 511];  // C = 512
    float src = (float)(j - 99) - dd;
    float fi = floorf(src);
    int i0 = (int)fi;
    float wf = src - fi;
    const float* base = x + (long)row * TLEN;
    float v0 = (i0 >= 0 && i0 < TLEN) ? base[i0] : 0.f;
    float v1 = (i0 + 1 >= 0 && i0 + 1 < TLEN) ? base[i0 + 1] : 0.f;
    xs[r][j] = v0 * (1.f - wf) + v1 * wf;
  }
  __syncthreads();
  const int r = tid / 80;
  const int l = tid - r * 80;
  if (l >= 75) return;
  const int t0 = 4 * l;
  const float* xr = &xs[r][99 + t0];
  float a0 = 0.f, a1 = 0.f, a2 = 0.f, a3 = 0.f;
  float4 p4 = *reinterpret_cast<const float4*>(xr + 1);
#pragma unroll
  for (int kg = 0; kg < 100; kg += 4) {
    const float4 e = *reinterpret_cast<const float4*>(eps + kg);
    const float4 n4 = *reinterpret_cast<const float4*>(xr - kg - 3);
    a0 += e.x * n4.w;  a1 += e.x * p4.x;  a2 += e.x * p4.y;  a3 += e.x * p4.z;
    a0 += e.y * n4.z;  a1 += e.y * n4.w;  a2 += e.y * p4.x;  a3 += e.y * p4.y;
    a0 += e.z * n4.y;  a1 += e.z * n4.z;  a2 += e.z * n4.w;  a3 += e.z * p4.x;
    a0 += e.w * n4.x;  a1 += e.w * n4.y;  a2 += e.w * n4.z;  a3 += e.w * n4.w;
    p4 = n4;
  }
  float4 res; res.x = a0; res.y = a1; res.z = a2; res.w = a3;
  *reinterpret_cast<float4*>(y + (long)(row0 + r) * TLEN + t0) = res;
}

// ---------------- spike: single-wave blocks, 64 rows, float4 tile loads ----------------
__global__ __launch_bounds__(64) void spike64_kernel(const float* __restrict__ u,
                                                     float* __restrict__ s, int rows) {
  __shared__ float tile[64][36];
  const int lane = threadIdx.x;
  const int row0 = blockIdx.x * 64;
  float ref = 0.f;
  for (int t0 = 0; t0 < TLEN; t0 += 32) {
    const int tw = (TLEN - t0 >= 32) ? 32 : (TLEN - t0);
#pragma unroll
    for (int q = 0; q < 8; ++q) {
      int i = q * 64 + lane;
      int rr = i >> 3, tq = i & 7;
      int grow = row0 + rr;
      int t = t0 + tq * 4;
      float4 v = {0.f, 0.f, 0.f, 0.f};
      if (grow < rows && t < TLEN)
        v = *reinterpret_cast<const float4*>(u + (long)grow * TLEN + t);
      *reinterpret_cast<float4*>(&tile[rr][tq * 4]) = v;
    }
    __syncthreads();
    if (tw == 32) {
#pragma unroll
      for (int c = 0; c < 32; ++c) {
        float v = tile[lane][c] + ref - THETA;
        float sp = (v >= 0.f) ? 1.f : 0.f;
        tile[lane][c] = sp;
        ref = REF_DECAY * ref - 20.0f * sp;
      }
    } else {
      for (int c = 0; c < 12; ++c) {
        float v = tile[lane][c] + ref - THETA;
        float sp = (v >= 0.f) ? 1.f : 0.f;
        tile[lane][c] = sp;
        ref = REF_DECAY * ref - 20.0f * sp;
      }
    }
    __syncthreads();
#pragma unroll
    for (int q = 0; q < 8; ++q) {
      int i = q * 64 + lane;
      int rr = i >> 3, tq = i & 7;
      int grow = row0 + rr;
      int t = t0 + tq * 4;
      if (grow < rows && t < TLEN) {
        float4 v = *reinterpret_cast<float4*>(&tile[rr][tq * 4]);
        *reinterpret_cast<float4*>(s + (long)grow * TLEN + t) = v;
      }
    }
    __syncthreads();
  }
}

// ---------------- spike + 4-way k-split partial reduce (fc1 epilogue) ----------------
__global__ __launch_bounds__(64) void spike_reduce4_kernel(const float* __restrict__ p,
                                                           float* __restrict__ s) {
  __shared__ float tile[64][36];
  const int lane = threadIdx.x;
  const int row0 = blockIdx.x * 64;
  float ref = 0.f;
  for (int t0 = 0; t0 < TLEN; t0 += 32) {
    const int tw = (TLEN - t0 >= 32) ? 32 : (TLEN - t0);
#pragma unroll
    for (int q = 0; q < 8; ++q) {
      int i = q * 64 + lane;
      int rr = i >> 3, tq = i & 7;
      int t = t0 + tq * 4;
      float4 v = {0.f, 0.f, 0.f, 0.f};
      if (t < TLEN) {
        long off = (long)(row0 + rr) * TLEN + t;
        const float4 v0 = *reinterpret_cast<const float4*>(p + off);
        const float4 v1 = *reinterpret_cast<const float4*>(p + 614400 + off);
        const float4 v2 = *reinterpret_cast<const float4*>(p + 1228800 + off);
        const float4 v3 = *reinterpret_cast<const float4*>(p + 1843200 + off);
        v.x = (v0.x + v1.x) + (v2.x + v3.x);
        v.y = (v0.y + v1.y) + (v2.y + v3.y);
        v.z = (v0.z + v1.z) + (v2.z + v3.z);
        v.w = (v0.w + v1.w) + (v2.w + v3.w);
      }
      *reinterpret_cast<float4*>(&tile[rr][tq * 4]) = v;
    }
    __syncthreads();
    if (tw == 32) {
#pragma unroll
      for (int c = 0; c < 32; ++c) {
        float v = tile[lane][c] + ref - THETA;
        float sp = (v >= 0.f) ? 1.f : 0.f;
        tile[lane][c] = sp;
        ref = REF_DECAY * ref - 20.0f * sp;
      }
    } else {
      for (int c = 0; c < 12; ++c) {
        float v = tile[lane][c] + ref - THETA;
        float sp = (v >= 0.f) ? 1.f : 0.f;
        tile[lane][c] = sp;
        ref = REF_DECAY * ref - 20.0f * sp;
      }
    }
    __syncthreads();
#pragma unroll
    for (int q = 0; q < 8; ++q) {
      int i = q * 64 + lane;
      int rr = i >> 3, tq = i & 7;
      int t = t0 + tq * 4;
      if (t < TLEN) {
        float4 v = *reinterpret_cast<float4*>(&tile[rr][tq * 4]);
        *reinterpret_cast<float4*>(s + (long)(row0 + rr) * TLEN + t) = v;
      }
    }
    __syncthreads();
  }
}

// ---------------- conv1: 2->16 ch, 5x5, pad 2, 32x32, float4 staging ----------------
__global__ __launch_bounds__(256) void conv1_kernel(const float* __restrict__ in,
                                                    const float* __restrict__ w,
                                                    float* __restrict__ out) {
  __shared__ float xl[11520];  // [c2][dy5][x36][t32]
  const int tid = threadIdx.x;
  const int t0 = blockIdx.x * 32;
  const int y = blockIdx.y;
  const int b = blockIdx.z;
  for (int i = tid; i < 2880; i += 256) {  // quads
    int tq = i & 7;
    int rest = i >> 3;
    int xp = rest % 36;
    int r2 = rest / 36;
    int dy = r2 % 5;
    int c = r2 / 5;
    int yy = y + dy - 2, xx = xp - 2, t = t0 + tq * 4;
    float4 v = {0.f, 0.f, 0.f, 0.f};
    if (yy >= 0 && yy < 32 && xx >= 0 && xx < 32 && t < TLEN)
      v = *reinterpret_cast<const float4*>(
          in + ((long)((b * 2 + c) * 32 + yy) * 32 + xx) * TLEN + t);
    *reinterpret_cast<float4*>(&xl[rest * 32 + tq * 4]) = v;
  }
  __syncthreads();
  const int tg = tid & 7;
  const int x = tid >> 3;
  float acc[16][4];
#pragma unroll
  for (int o = 0; o < 16; ++o) { acc[o][0] = acc[o][1] = acc[o][2] = acc[o][3] = 0.f; }
  for (int c = 0; c < 2; ++c)
#pragma unroll
    for (int dy = 0; dy < 5; ++dy)
#pragma unroll
      for (int kx = 0; kx < 5; ++kx) {
        const float4 xv = *reinterpret_cast<const float4*>(
            &xl[((c * 5 + dy) * 36 + x + kx) * 32 + tg * 4]);
        const float* wp = w + (c * 5 + dy) * 5 + kx;
#pragma unroll
        for (int o = 0; o < 16; ++o) {
          float wsc = wp[o * 50];
          acc[o][0] += wsc * xv.x; acc[o][1] += wsc * xv.y;
          acc[o][2] += wsc * xv.z; acc[o][3] += wsc * xv.w;
        }
      }
  const int t = t0 + tg * 4;
  if (t < TLEN) {
#pragma unroll
    for (int o = 0; o < 16; ++o) {
      float4 res; res.x = acc[o][0]; res.y = acc[o][1]; res.z = acc[o][2]; res.w = acc[o][3];
      *reinterpret_cast<float4*>(&out[((long)((b * 16 + o) * 32 + y) * 32 + x) * TLEN + t]) = res;
    }
  }
}

// ---------------- conv2: 16->32 ch, 3x3, pad 1, 16x16, float4 staging ----------------
__global__ __launch_bounds__(256) void conv2_kernel(const float* __restrict__ in,
                                                    const float* __restrict__ w,
                                                    float* __restrict__ out) {
  __shared__ float xl[13824];  // [c16][dy3][x18][t16]
  const int tid = threadIdx.x;
  const int t0 = blockIdx.x * 16;
  const int y = blockIdx.y;
  const int b = blockIdx.z;
  for (int i = tid; i < 3456; i += 256) {  // quads
    int tq = i & 3;
    int rest = i >> 2;
    int xp = rest % 18;
    int r2 = rest / 18;
    int dy = r2 % 3;
    int c = r2 / 3;
    int yy = y + dy - 1, xx = xp - 1, t = t0 + tq * 4;
    float4 v = {0.f, 0.f, 0.f, 0.f};
    if (yy >= 0 && yy < 16 && xx >= 0 && xx < 16 && t < TLEN)
      v = *reinterpret_cast<const float4*>(
          in + ((long)((b * 16 + c) * 16 + yy) * 16 + xx) * TLEN + t);
    *reinterpret_cast<float4*>(&xl[rest * 16 + tq * 4]) = v;
  }
  __syncthreads();
  const int tg = tid & 3;
  const int x = (tid >> 2) & 15;
  const int oh = tid >> 6;
  float acc[8][4];
#pragma unroll
  for (int o = 0; o < 8; ++o) { acc[o][0] = acc[o][1] = acc[o][2] = acc[o][3] = 0.f; }
  for (int c = 0; c < 16; ++c)
#pragma unroll
    for (int dy = 0; dy < 3; ++dy)
#pragma unroll
      for (int kx = 0; kx < 3; ++kx) {
        const float4 xv = *reinterpret_cast<const float4*>(
            &xl[((c * 3 + dy) * 18 + x + kx) * 16 + tg * 4]);
        const float* wp = w + (c * 3 + dy) * 3 + kx;
#pragma unroll
        for (int oo = 0; oo < 8; ++oo) {
          float wsc = wp[(oh * 8 + oo) * 144];
          acc[oo][0] += wsc * xv.x; acc[oo][1] += wsc * xv.y;
          acc[oo][2] += wsc * xv.z; acc[oo][3] += wsc * xv.w;
        }
      }
  const int t = t0 + tg * 4;
  if (t < TLEN) {
#pragma unroll
    for (int oo = 0; oo < 8; ++oo) {
      int o = oh * 8 + oo;
      float4 res; res.x = acc[oo][0]; res.y = acc[oo][1]; res.z = acc[oo][2]; res.w = acc[oo][3];
      *reinterpret_cast<float4*>(&out[((long)((b * 32 + o) * 16 + y) * 16 + x) * TLEN + t]) = res;
    }
  }
}

// ---------------- fused delay + 2x2 pool, scale 2.75 ----------------
__global__ __launch_bounds__(256) void pool2_delay_kernel(const float* __restrict__ in,
                                                          const float* __restrict__ d,
                                                          float* __restrict__ out,
                                                          int C, int HO, int WO, int total) {
  int idx = blockIdx.x * 256 + threadIdx.x;
  if (idx >= total) return;
  int t = idx % TLEN;
  int rest = idx / TLEN;
  int x = rest % WO; rest /= WO;
  int y = rest % HO; rest /= HO;
  int c = rest % C;
  int b = rest / C;
  float dd = d[c];
  float src = (float)t - dd;
  float fi = floorf(src);
  int i0 = (int)fi;
  float wf = src - fi;
  const float* base = in + (((long)(b * C + c) * (2 * HO) + 2 * y) * (2 * WO) + 2 * x) * TLEN;
  long rs = (long)(2 * WO) * TLEN;
  bool ok0 = (i0 >= 0) && (i0 < TLEN);
  bool ok1 = (i0 + 1 >= 0) && (i0 + 1 < TLEN);
  int j0 = min(max(i0, 0), TLEN - 1);
  int j1 = min(max(i0 + 1, 0), TLEN - 1);
  float s0 = 0.f, s1 = 0.f;
#pragma unroll
  for (int dy = 0; dy < 2; ++dy)
#pragma unroll
    for (int dx = 0; dx < 2; ++dx) {
      const float* p = base + dy * rs + dx * TLEN;
      s0 += ok0 ? p[j0] : 0.f;
      s1 += ok1 ? p[j1] : 0.f;
    }
  out[idx] = (s0 * (1.f - wf) + s1 * wf) * 2.75f;
}

// ---------------- fc1: k-split x4, 64x64 tiles, float4 staging, partials out ----------------
__global__ __launch_bounds__(256) void fc1_kernel(const float* __restrict__ x,
                                                  const float* __restrict__ w,
                                                  float* __restrict__ part) {
  __shared__ float wl[64][44];   // [o][k] non-transposed, pad 44
  __shared__ float xlb[32][68];  // [k][t], pad 68
  const int tid = threadIdx.x;
  const int t0 = blockIdx.x * 64;
  const int o0 = blockIdx.y * 64;
  const int b = blockIdx.z >> 2;
  const int split = blockIdx.z & 3;
  const int tx = tid & 15, ty = tid >> 4;
  float acc[4][4];
#pragma unroll
  for (int i = 0; i < 4; ++i)
#pragma unroll
    for (int j = 0; j < 4; ++j) acc[i][j] = 0.f;
  const int kbeg = split * 512;
  for (int kc = kbeg; kc < kbeg + 512; kc += 32) {
    __syncthreads();
#pragma unroll
    for (int rr = 0; rr < 2; ++rr) {
      int i = rr * 256 + tid;  // 0..511
      int ol = i >> 3, kq = i & 7;
      float4 v = *reinterpret_cast<const float4*>(w + (long)(o0 + ol) * 2048 + kc + kq * 4);
      *reinterpret_cast<float4*>(&wl[ol][kq * 4]) = v;
    }
#pragma unroll
    for (int rr = 0; rr < 2; ++rr) {
      int i = rr * 256 + tid;
      int kl = i >> 4, tq = i & 15;
      int t = t0 + tq * 4;
      float4 v = {0.f, 0.f, 0.f, 0.f};
      if (t < TLEN)
        v = *reinterpret_cast<const float4*>(x + ((long)b * 2048 + kc + kl) * TLEN + t);
      *reinterpret_cast<float4*>(&xlb[kl][tq * 4]) = v;
    }
    __syncthreads();
#pragma unroll
    for (int k4 = 0; k4 < 8; ++k4) {
      float4 wq[4], xq[4];
#pragma unroll
      for (int i = 0; i < 4; ++i)
        wq[i] = *reinterpret_cast<const float4*>(&wl[ty * 4 + i][k4 * 4]);
#pragma unroll
      for (int j = 0; j < 4; ++j)
        xq[j] = *reinterpret_cast<const float4*>(&xlb[k4 * 4 + j][tx * 4]);
#pragma unroll
      for (int i = 0; i < 4; ++i) {
        float wa[4] = {wq[i].x, wq[i].y, wq[i].z, wq[i].w};
#pragma unroll
        for (int j = 0; j < 4; ++j) {
          float xa[4] = {xq[j].x, xq[j].y, xq[j].z, xq[j].w};
          acc[i][0] += wa[j] * xa[0]; acc[i][1] += wa[j] * xa[1];
          acc[i][2] += wa[j] * xa[2]; acc[i][3] += wa[j] * xa[3];
        }
      }
    }
  }
  const int t = t0 + tx * 4;
  if (t < TLEN) {
#pragma unroll
    for (int i = 0; i < 4; ++i) {
      float4 res; res.x = acc[i][0]; res.y = acc[i][1]; res.z = acc[i][2]; res.w = acc[i][3];
      *reinterpret_cast<float4*>(
          part + ((long)(split * 4 + b) * 512 + o0 + ty * 4 + i) * TLEN + t) = res;
    }
  }
}

// ---------------- fc2 + final spike scan fused, writes d_out ----------------
__global__ __launch_bounds__(320) void fc2_spike_kernel(const float* __restrict__ x,
                                                        const float* __restrict__ w,
                                                        float* __restrict__ out) {
  __shared__ float ul[304];
  int blk = blockIdx.x;
  int b = blk / 11, o = blk % 11;
  int t = threadIdx.x;
  if (t < TLEN) {
    const float* xr = x + (long)b * 512 * TLEN + t;
    const float* wr = w + o * 512;
    float a0 = 0.f, a1 = 0.f, a2 = 0.f, a3 = 0.f;
#pragma unroll 4
    for (int i = 0; i < 512; i += 4) {
      a0 += wr[i] * xr[(long)i * TLEN];
      a1 += wr[i + 1] * xr[(long)(i + 1) * TLEN];
      a2 += wr[i + 2] * xr[(long)(i + 2) * TLEN];
      a3 += wr[i + 3] * xr[(long)(i + 3) * TLEN];
    }
    ul[t] = (a0 + a1) + (a2 + a3);
  }
  __syncthreads();
  if (t == 0) {
    float ref = 0.f;
#pragma unroll 4
    for (int c = 0; c < TLEN; ++c) {
      float v = ul[c] + ref - THETA;
      float sp = (v >= 0.f) ? 1.f : 0.f;
      ul[c] = sp;
      ref = REF_DECAY * ref - 20.0f * sp;
    }
  }
  __syncthreads();
  if (t < TLEN) out[((long)b * 11 + o) * TLEN + t] = ul[t];
}

extern "C" void kernel_launch(void* const* d_in, const int* in_sizes, int n_in,
                              void* d_out, int out_size, void* d_ws, size_t ws_size,
                              hipStream_t stream) {
  const float* input = (const float*)d_in[0];
  const float* w1    = (const float*)d_in[1];
  const float* w2    = (const float*)d_in[2];
  const float* wfc1  = (const float*)d_in[3];
  const float* wfc2  = (const float*)d_in[4];
  const float* d1    = (const float*)d_in[5];
  const float* d2    = (const float*)d_in[6];
  const float* d3    = (const float*)d_in[7];

  float* ws   = (float*)d_ws;
  float* big0 = ws;                    // 19,660,800 floats (also fc1 partials 4x614400)
  float* medA = big0 + 19660800;
  float* medB = medA + 4915200;
  float* fcA  = medB + 4915200;
  float* fcB  = fcA + 614400;
  float* eps  = fcB + 614400;

  hipLaunchKernelGGL(eps_init_kernel, dim3(1), dim3(128), 0, stream, eps);

  // L1: spike(psp(pool4(input)))
  hipLaunchKernelGGL(pool4_kernel, dim3(600), dim3(256), 0, stream, input, medA);
  hipLaunchKernelGGL(psp_spike_kernel, dim3(2048), dim3(320), 0, stream, medA, medB, eps, 8192);
  // L2: spike(conv1(psp(S0)))
  hipLaunchKernelGGL(psp_kernel, dim3(2048), dim3(320), 0, stream, medB, medA, eps, 8192);
  hipLaunchKernelGGL(conv1_kernel, dim3(10, 32, 4), dim3(256), 0, stream, medA, w1, big0);
  hipLaunchKernelGGL(spike64_kernel, dim3(1024), dim3(64), 0, stream, big0, big0, 65536);
  // L3: spike(psp(pool2(delay1(S1))))
  hipLaunchKernelGGL(pool2_delay_kernel, dim3(19200), dim3(256), 0, stream,
                     big0, d1, medA, 16, 16, 16, 4915200);
  hipLaunchKernelGGL(psp_spike_kernel, dim3(4096), dim3(320), 0, stream, medA, medB, eps, 16384);
  // L4: spike(conv2(psp(S2)))
  hipLaunchKernelGGL(psp_kernel, dim3(4096), dim3(320), 0, stream, medB, medA, eps, 16384);
  hipLaunchKernelGGL(conv2_kernel, dim3(19, 16, 4), dim3(256), 0, stream, medA, w2, big0);
  hipLaunchKernelGGL(spike64_kernel, dim3(512), dim3(64), 0, stream, big0, big0, 32768);
  // L5: spike(psp(pool2(delay2(S3))))
  hipLaunchKernelGGL(pool2_delay_kernel, dim3(9600), dim3(256), 0, stream,
                     big0, d2, medA, 32, 8, 8, 2457600);
  hipLaunchKernelGGL(psp_spike_kernel, dim3(2048), dim3(320), 0, stream, medA, medB, eps, 8192);
  // L6: spike(fc1(psp(S4)))
  hipLaunchKernelGGL(psp_kernel, dim3(2048), dim3(320), 0, stream, medB, medA, eps, 8192);
  hipLaunchKernelGGL(fc1_kernel, dim3(5, 8, 16), dim3(256), 0, stream, medA, wfc1, big0);
  hipLaunchKernelGGL(spike_reduce4_kernel, dim3(32), dim3(64), 0, stream, big0, fcA);
  // L7: spike(fc2(psp(delay3(S5)))) -> d_out
  hipLaunchKernelGGL(psp_delay_kernel, dim3(512), dim3(320), 0, stream, fcA, fcB, eps, d3, 2048);
  hipLaunchKernelGGL(fc2_spike_kernel, dim3(44), dim3(320), 0, stream, fcB, wfc2, (float*)d_out);
}

// Round 3
// 552.208 us; speedup vs baseline: 2.4774x; 1.1682x over previous
//
#include <hip/hip_runtime.h>

#define TLEN 300
#define THETA 10.0f
#define REF_DECAY 0.36787944117144233f

// ---------------- eps table: eps[k] = (k/10) * exp(1 - k/10), k=0..99 ----------------
__global__ void eps_init_kernel(float* __restrict__ eps) {
  int k = threadIdx.x;
  if (k < 100) {
    float a = (float)k / 10.0f;
    eps[k] = a * expf(1.0f - a);
  }
}

// ---------------- 4x4 sum-pool on raw input (float4 over t), scale 0.6875 ----------------
__global__ __launch_bounds__(256) void pool4_kernel(const float* __restrict__ in,
                                                    float* __restrict__ out) {
  int idx = blockIdx.x * 256 + threadIdx.x;  // quad index
  if (idx >= 153600) return;
  int tq = idx % 75;
  int rest = idx / 75;
  int x = rest & 31; rest >>= 5;
  int y = rest & 31; rest >>= 5;  // rest = bc (0..7)
  const float* base = in + ((long)(rest * 128 + y * 4) * 128 + x * 4) * TLEN + tq * 4;
  float4 s = {0.f, 0.f, 0.f, 0.f};
#pragma unroll
  for (int dy = 0; dy < 4; ++dy)
#pragma unroll
    for (int dx = 0; dx < 4; ++dx) {
      float4 v = *reinterpret_cast<const float4*>(base + (dy * 128 + dx) * TLEN);
      s.x += v.x; s.y += v.y; s.z += v.z; s.w += v.w;
    }
  s.x *= 0.6875f; s.y *= 0.6875f; s.z *= 0.6875f; s.w *= 0.6875f;
  *reinterpret_cast<float4*>(out + ((long)(rest * 32 + y) * 32 + x) * TLEN + tq * 4) = s;
}

// ---------------- 100-tap FIR core: 8 outputs/lane, 32 FMA per ds_read_b128 ----------------
// rowbase = &row[0]; data lives at [100..399], zeros at [0..99] and [400..403].
// Computes acc[j] = sum_k eps[k] * x[8l + j - k], k ascending (same order as prior rounds).
__device__ __forceinline__ void fir100(const float* rowbase, int l,
                                       const float* epss, float acc[8]) {
  const float* p = rowbase + 100 + 8 * l;
  float4 A = *reinterpret_cast<const float4*>(p - 4);
  float4 B = *reinterpret_cast<const float4*>(p);
  float4 C = *reinterpret_cast<const float4*>(p + 4);
#pragma unroll
  for (int j = 0; j < 8; ++j) acc[j] = 0.f;
#pragma unroll
  for (int kg = 0; kg < 100; kg += 4) {
    const float4 e = *reinterpret_cast<const float4*>(epss + kg);
    acc[0] += e.x * B.x; acc[1] += e.x * B.y; acc[2] += e.x * B.z; acc[3] += e.x * B.w;
    acc[4] += e.x * C.x; acc[5] += e.x * C.y; acc[6] += e.x * C.z; acc[7] += e.x * C.w;
    acc[0] += e.y * A.w; acc[1] += e.y * B.x; acc[2] += e.y * B.y; acc[3] += e.y * B.z;
    acc[4] += e.y * B.w; acc[5] += e.y * C.x; acc[6] += e.y * C.y; acc[7] += e.y * C.z;
    acc[0] += e.z * A.z; acc[1] += e.z * A.w; acc[2] += e.z * B.x; acc[3] += e.z * B.y;
    acc[4] += e.z * B.z; acc[5] += e.z * B.w; acc[6] += e.z * C.x; acc[7] += e.z * C.y;
    acc[0] += e.w * A.y; acc[1] += e.w * A.z; acc[2] += e.w * A.w; acc[3] += e.w * B.x;
    acc[4] += e.w * B.y; acc[5] += e.w * B.z; acc[6] += e.w * B.w; acc[7] += e.w * C.x;
    C = B; B = A;
    if (kg < 96) A = *reinterpret_cast<const float4*>(p - kg - 8);
  }
}

// 16 parallel row-scans (lane = row). Stride 404 floats -> 2-way bank alias (free).
__device__ __forceinline__ void scan16(float (*xs)[404], int tid) {
  if (tid < 16) {
    float ref = 0.f;
    float* row = &xs[tid][100];
    for (int c4 = 0; c4 < 75; ++c4) {
      float4 u = *reinterpret_cast<float4*>(row + 4 * c4);
      float v, sp;
      v = u.x + ref - THETA; sp = (v >= 0.f) ? 1.f : 0.f; u.x = sp; ref = REF_DECAY * ref - 20.0f * sp;
      v = u.y + ref - THETA; sp = (v >= 0.f) ? 1.f : 0.f; u.y = sp; ref = REF_DECAY * ref - 20.0f * sp;
      v = u.z + ref - THETA; sp = (v >= 0.f) ? 1.f : 0.f; u.z = sp; ref = REF_DECAY * ref - 20.0f * sp;
      v = u.w + ref - THETA; sp = (v >= 0.f) ? 1.f : 0.f; u.w = sp; ref = REF_DECAY * ref - 20.0f * sp;
      *reinterpret_cast<float4*>(row + 4 * c4) = u;
    }
  }
}

// ---------------- fused psp -> spike -> psp (16 rows/block) ----------------
// in: membrane input rows [rows][300]; out: psp(spike(psp(in))) rows [rows][300]
__global__ __launch_bounds__(256) void psp_spike_psp_kernel(const float* __restrict__ in,
                                                            float* __restrict__ out,
                                                            const float* __restrict__ epsg) {
  __shared__ float xs[16][404];
  __shared__ float xs2[16][404];
  __shared__ float epss[104];
  const int tid = threadIdx.x;
  const int row0 = blockIdx.x * 16;
  if (tid < 104) epss[tid] = (tid < 100) ? epsg[tid] : 0.f;
  for (int i = tid; i < 1664; i += 256) {  // zero 100 front + 4 tail pads, both buffers
    int r = i / 104, j = i - r * 104;
    int idx = (j < 100) ? j : 300 + j;
    xs[r][idx] = 0.f;
    xs2[r][idx] = 0.f;
  }
  for (int i = tid; i < 1200; i += 256) {  // stage input (coalesced, aligned)
    int r = i / 75, q = i - r * 75;
    float4 v = *reinterpret_cast<const float4*>(in + (long)(row0 + r) * TLEN + 4 * q);
    *reinterpret_cast<float4*>(&xs[r][100 + 4 * q]) = v;
  }
  __syncthreads();
  // FIR1: xs -> xs2 (membrane potential u)
  for (int task = tid; task < 608; task += 256) {
    int r = task & 15, l = task >> 4;
    float acc[8];
    fir100(&xs[r][0], l, epss, acc);
    float4 q1; q1.x = acc[0]; q1.y = acc[1]; q1.z = acc[2]; q1.w = acc[3];
    *reinterpret_cast<float4*>(&xs2[r][100 + 8 * l]) = q1;
    if (8 * l + 4 < TLEN) {
      float4 q2; q2.x = acc[4]; q2.y = acc[5]; q2.z = acc[6]; q2.w = acc[7];
      *reinterpret_cast<float4*>(&xs2[r][104 + 8 * l]) = q2;
    }
  }
  __syncthreads();
  scan16(xs2, tid);  // u -> spikes, in place
  __syncthreads();
  // FIR2 on spike train -> global (psp of spikes, feeds next layer's conv/fc)
  for (int task = tid; task < 608; task += 256) {
    int r = task & 15, l = task >> 4;
    float acc[8];
    fir100(&xs2[r][0], l, epss, acc);
    long off = (long)(row0 + r) * TLEN + 8 * l;
    float4 q1; q1.x = acc[0]; q1.y = acc[1]; q1.z = acc[2]; q1.w = acc[3];
    *reinterpret_cast<float4*>(out + off) = q1;
    if (8 * l + 4 < TLEN) {
      float4 q2; q2.x = acc[4]; q2.y = acc[5]; q2.z = acc[6]; q2.w = acc[7];
      *reinterpret_cast<float4*>(out + off + 4) = q2;
    }
  }
}

// ---------------- fc1 partial reduce + spike + delay3 + psp (L6 epilogue + L7 head) ----------------
__global__ __launch_bounds__(256) void reduce_spike_delay_psp_kernel(
    const float* __restrict__ part, const float* __restrict__ d,
    float* __restrict__ out, const float* __restrict__ epsg) {
  __shared__ float xs[16][404];
  __shared__ float xs2[16][404];
  __shared__ float epss[104];
  const int tid = threadIdx.x;
  const int row0 = blockIdx.x * 16;
  if (tid < 104) epss[tid] = (tid < 100) ? epsg[tid] : 0.f;
  for (int i = tid; i < 1664; i += 256) {
    int r = i / 104, j = i - r * 104;
    int idx = (j < 100) ? j : 300 + j;
    xs[r][idx] = 0.f;
    xs2[r][idx] = 0.f;
  }
  for (int i = tid; i < 1200; i += 256) {  // sum 4 k-split partials
    int r = i / 75, q = i - r * 75;
    long off = (long)(row0 + r) * TLEN + 4 * q;
    const float4 v0 = *reinterpret_cast<const float4*>(part + off);
    const float4 v1 = *reinterpret_cast<const float4*>(part + 614400 + off);
    const float4 v2 = *reinterpret_cast<const float4*>(part + 1228800 + off);
    const float4 v3 = *reinterpret_cast<const float4*>(part + 1843200 + off);
    float4 v;
    v.x = (v0.x + v1.x) + (v2.x + v3.x);
    v.y = (v0.y + v1.y) + (v2.y + v3.y);
    v.z = (v0.z + v1.z) + (v2.z + v3.z);
    v.w = (v0.w + v1.w) + (v2.w + v3.w);
    *reinterpret_cast<float4*>(&xs[r][100 + 4 * q]) = v;
  }
  __syncthreads();
  scan16(xs, tid);  // u -> spikes S5
  __syncthreads();
  // delay3 (per-channel lerp) into xs2; front zeros serve the OOB mask
  for (int i = tid; i < 1200; i += 256) {
    int r = i / 75, q = i - r * 75;
    float dd = d[(row0 + r) & 511];
#pragma unroll
    for (int j = 0; j < 4; ++j) {
      int t = 4 * q + j;
      float src = (float)t - dd;
      float fi = floorf(src);
      int i0 = (int)fi;        // in [-4, 299]
      float w = src - fi;
      float v0 = xs[r][100 + i0];
      float v1 = xs[r][101 + i0];
      xs2[r][100 + t] = v0 * (1.f - w) + v1 * w;
    }
  }
  __syncthreads();
  // psp(delay3(S5)) -> global (feeds fc2)
  for (int task = tid; task < 608; task += 256) {
    int r = task & 15, l = task >> 4;
    float acc[8];
    fir100(&xs2[r][0], l, epss, acc);
    long off = (long)(row0 + r) * TLEN + 8 * l;
    float4 q1; q1.x = acc[0]; q1.y = acc[1]; q1.z = acc[2]; q1.w = acc[3];
    *reinterpret_cast<float4*>(out + off) = q1;
    if (8 * l + 4 < TLEN) {
      float4 q2; q2.x = acc[4]; q2.y = acc[5]; q2.z = acc[6]; q2.w = acc[7];
      *reinterpret_cast<float4*>(out + off + 4) = q2;
    }
  }
}

// ---------------- spike: single-wave blocks, 64 rows, float4 tile loads ----------------
__global__ __launch_bounds__(64) void spike64_kernel(const float* __restrict__ u,
                                                     float* __restrict__ s, int rows) {
  __shared__ float tile[64][36];
  const int lane = threadIdx.x;
  const int row0 = blockIdx.x * 64;
  float ref = 0.f;
  for (int t0 = 0; t0 < TLEN; t0 += 32) {
    const int tw = (TLEN - t0 >= 32) ? 32 : (TLEN - t0);
#pragma unroll
    for (int q = 0; q < 8; ++q) {
      int i = q * 64 + lane;
      int rr = i >> 3, tq = i & 7;
      int grow = row0 + rr;
      int t = t0 + tq * 4;
      float4 v = {0.f, 0.f, 0.f, 0.f};
      if (grow < rows && t < TLEN)
        v = *reinterpret_cast<const float4*>(u + (long)grow * TLEN + t);
      *reinterpret_cast<float4*>(&tile[rr][tq * 4]) = v;
    }
    __syncthreads();
    if (tw == 32) {
#pragma unroll
      for (int c = 0; c < 32; ++c) {
        float v = tile[lane][c] + ref - THETA;
        float sp = (v >= 0.f) ? 1.f : 0.f;
        tile[lane][c] = sp;
        ref = REF_DECAY * ref - 20.0f * sp;
      }
    } else {
      for (int c = 0; c < 12; ++c) {
        float v = tile[lane][c] + ref - THETA;
        float sp = (v >= 0.f) ? 1.f : 0.f;
        tile[lane][c] = sp;
        ref = REF_DECAY * ref - 20.0f * sp;
      }
    }
    __syncthreads();
#pragma unroll
    for (int q = 0; q < 8; ++q) {
      int i = q * 64 + lane;
      int rr = i >> 3, tq = i & 7;
      int grow = row0 + rr;
      int t = t0 + tq * 4;
      if (grow < rows && t < TLEN) {
        float4 v = *reinterpret_cast<float4*>(&tile[rr][tq * 4]);
        *reinterpret_cast<float4*>(s + (long)grow * TLEN + t) = v;
      }
    }
    __syncthreads();
  }
}

// ---------------- conv1: 2->16 ch, 5x5, pad 2, 32x32, float4 staging ----------------
__global__ __launch_bounds__(256) void conv1_kernel(const float* __restrict__ in,
                                                    const float* __restrict__ w,
                                                    float* __restrict__ out) {
  __shared__ float xl[11520];  // [c2][dy5][x36][t32]
  const int tid = threadIdx.x;
  const int t0 = blockIdx.x * 32;
  const int y = blockIdx.y;
  const int b = blockIdx.z;
  for (int i = tid; i < 2880; i += 256) {  // quads
    int tq = i & 7;
    int rest = i >> 3;
    int xp = rest % 36;
    int r2 = rest / 36;
    int dy = r2 % 5;
    int c = r2 / 5;
    int yy = y + dy - 2, xx = xp - 2, t = t0 + tq * 4;
    float4 v = {0.f, 0.f, 0.f, 0.f};
    if (yy >= 0 && yy < 32 && xx >= 0 && xx < 32 && t < TLEN)
      v = *reinterpret_cast<const float4*>(
          in + ((long)((b * 2 + c) * 32 + yy) * 32 + xx) * TLEN + t);
    *reinterpret_cast<float4*>(&xl[rest * 32 + tq * 4]) = v;
  }
  __syncthreads();
  const int tg = tid & 7;
  const int x = tid >> 3;
  float acc[16][4];
#pragma unroll
  for (int o = 0; o < 16; ++o) { acc[o][0] = acc[o][1] = acc[o][2] = acc[o][3] = 0.f; }
  for (int c = 0; c < 2; ++c)
#pragma unroll
    for (int dy = 0; dy < 5; ++dy)
#pragma unroll
      for (int kx = 0; kx < 5; ++kx) {
        const float4 xv = *reinterpret_cast<const float4*>(
            &xl[((c * 5 + dy) * 36 + x + kx) * 32 + tg * 4]);
        const float* wp = w + (c * 5 + dy) * 5 + kx;
#pragma unroll
        for (int o = 0; o < 16; ++o) {
          float wsc = wp[o * 50];
          acc[o][0] += wsc * xv.x; acc[o][1] += wsc * xv.y;
          acc[o][2] += wsc * xv.z; acc[o][3] += wsc * xv.w;
        }
      }
  const int t = t0 + tg * 4;
  if (t < TLEN) {
#pragma unroll
    for (int o = 0; o < 16; ++o) {
      float4 res; res.x = acc[o][0]; res.y = acc[o][1]; res.z = acc[o][2]; res.w = acc[o][3];
      *reinterpret_cast<float4*>(&out[((long)((b * 16 + o) * 32 + y) * 32 + x) * TLEN + t]) = res;
    }
  }
}

// ---------------- conv2: 16->32 ch, 3x3, pad 1, 16x16, float4 staging ----------------
__global__ __launch_bounds__(256) void conv2_kernel(const float* __restrict__ in,
                                                    const float* __restrict__ w,
                                                    float* __restrict__ out) {
  __shared__ float xl[13824];  // [c16][dy3][x18][t16]
  const int tid = threadIdx.x;
  const int t0 = blockIdx.x * 16;
  const int y = blockIdx.y;
  const int b = blockIdx.z;
  for (int i = tid; i < 3456; i += 256) {  // quads
    int tq = i & 3;
    int rest = i >> 2;
    int xp = rest % 18;
    int r2 = rest / 18;
    int dy = r2 % 3;
    int c = r2 / 3;
    int yy = y + dy - 1, xx = xp - 1, t = t0 + tq * 4;
    float4 v = {0.f, 0.f, 0.f, 0.f};
    if (yy >= 0 && yy < 16 && xx >= 0 && xx < 16 && t < TLEN)
      v = *reinterpret_cast<const float4*>(
          in + ((long)((b * 16 + c) * 16 + yy) * 16 + xx) * TLEN + t);
    *reinterpret_cast<float4*>(&xl[rest * 16 + tq * 4]) = v;
  }
  __syncthreads();
  const int tg = tid & 3;
  const int x = (tid >> 2) & 15;
  const int oh = tid >> 6;
  float acc[8][4];
#pragma unroll
  for (int o = 0; o < 8; ++o) { acc[o][0] = acc[o][1] = acc[o][2] = acc[o][3] = 0.f; }
  for (int c = 0; c < 16; ++c)
#pragma unroll
    for (int dy = 0; dy < 3; ++dy)
#pragma unroll
      for (int kx = 0; kx < 3; ++kx) {
        const float4 xv = *reinterpret_cast<const float4*>(
            &xl[((c * 3 + dy) * 18 + x + kx) * 16 + tg * 4]);
        const float* wp = w + (c * 3 + dy) * 3 + kx;
#pragma unroll
        for (int oo = 0; oo < 8; ++oo) {
          float wsc = wp[(oh * 8 + oo) * 144];
          acc[oo][0] += wsc * xv.x; acc[oo][1] += wsc * xv.y;
          acc[oo][2] += wsc * xv.z; acc[oo][3] += wsc * xv.w;
        }
      }
  const int t = t0 + tg * 4;
  if (t < TLEN) {
#pragma unroll
    for (int oo = 0; oo < 8; ++oo) {
      int o = oh * 8 + oo;
      float4 res; res.x = acc[oo][0]; res.y = acc[oo][1]; res.z = acc[oo][2]; res.w = acc[oo][3];
      *reinterpret_cast<float4*>(&out[((long)((b * 32 + o) * 16 + y) * 16 + x) * TLEN + t]) = res;
    }
  }
}

// ---------------- fused delay + 2x2 pool, scale 2.75 ----------------
__global__ __launch_bounds__(256) void pool2_delay_kernel(const float* __restrict__ in,
                                                          const float* __restrict__ d,
                                                          float* __restrict__ out,
                                                          int C, int HO, int WO, int total) {
  int idx = blockIdx.x * 256 + threadIdx.x;
  if (idx >= total) return;
  int t = idx % TLEN;
  int rest = idx / TLEN;
  int x = rest % WO; rest /= WO;
  int y = rest % HO; rest /= HO;
  int c = rest % C;
  int b = rest / C;
  float dd = d[c];
  float src = (float)t - dd;
  float fi = floorf(src);
  int i0 = (int)fi;
  float wf = src - fi;
  const float* base = in + (((long)(b * C + c) * (2 * HO) + 2 * y) * (2 * WO) + 2 * x) * TLEN;
  long rs = (long)(2 * WO) * TLEN;
  bool ok0 = (i0 >= 0) && (i0 < TLEN);
  bool ok1 = (i0 + 1 >= 0) && (i0 + 1 < TLEN);
  int j0 = min(max(i0, 0), TLEN - 1);
  int j1 = min(max(i0 + 1, 0), TLEN - 1);
  float s0 = 0.f, s1 = 0.f;
#pragma unroll
  for (int dy = 0; dy < 2; ++dy)
#pragma unroll
    for (int dx = 0; dx < 2; ++dx) {
      const float* p = base + dy * rs + dx * TLEN;
      s0 += ok0 ? p[j0] : 0.f;
      s1 += ok1 ? p[j1] : 0.f;
    }
  out[idx] = (s0 * (1.f - wf) + s1 * wf) * 2.75f;
}

// ---------------- fc1: k-split x4, 64x64 tiles, float4 staging, partials out ----------------
__global__ __launch_bounds__(256) void fc1_kernel(const float* __restrict__ x,
                                                  const float* __restrict__ w,
                                                  float* __restrict__ part) {
  __shared__ float wl[64][44];   // [o][k] non-transposed, pad 44
  __shared__ float xlb[32][68];  // [k][t], pad 68
  const int tid = threadIdx.x;
  const int t0 = blockIdx.x * 64;
  const int o0 = blockIdx.y * 64;
  const int b = blockIdx.z >> 2;
  const int split = blockIdx.z & 3;
  const int tx = tid & 15, ty = tid >> 4;
  float acc[4][4];
#pragma unroll
  for (int i = 0; i < 4; ++i)
#pragma unroll
    for (int j = 0; j < 4; ++j) acc[i][j] = 0.f;
  const int kbeg = split * 512;
  for (int kc = kbeg; kc < kbeg + 512; kc += 32) {
    __syncthreads();
#pragma unroll
    for (int rr = 0; rr < 2; ++rr) {
      int i = rr * 256 + tid;  // 0..511
      int ol = i >> 3, kq = i & 7;
      float4 v = *reinterpret_cast<const float4*>(w + (long)(o0 + ol) * 2048 + kc + kq * 4);
      *reinterpret_cast<float4*>(&wl[ol][kq * 4]) = v;
    }
#pragma unroll
    for (int rr = 0; rr < 2; ++rr) {
      int i = rr * 256 + tid;
      int kl = i >> 4, tq = i & 15;
      int t = t0 + tq * 4;
      float4 v = {0.f, 0.f, 0.f, 0.f};
      if (t < TLEN)
        v = *reinterpret_cast<const float4*>(x + ((long)b * 2048 + kc + kl) * TLEN + t);
      *reinterpret_cast<float4*>(&xlb[kl][tq * 4]) = v;
    }
    __syncthreads();
#pragma unroll
    for (int k4 = 0; k4 < 8; ++k4) {
      float4 wq[4], xq[4];
#pragma unroll
      for (int i = 0; i < 4; ++i)
        wq[i] = *reinterpret_cast<const float4*>(&wl[ty * 4 + i][k4 * 4]);
#pragma unroll
      for (int j = 0; j < 4; ++j)
        xq[j] = *reinterpret_cast<const float4*>(&xlb[k4 * 4 + j][tx * 4]);
#pragma unroll
      for (int i = 0; i < 4; ++i) {
        float wa[4] = {wq[i].x, wq[i].y, wq[i].z, wq[i].w};
#pragma unroll
        for (int j = 0; j < 4; ++j) {
          float xa[4] = {xq[j].x, xq[j].y, xq[j].z, xq[j].w};
          acc[i][0] += wa[j] * xa[0]; acc[i][1] += wa[j] * xa[1];
          acc[i][2] += wa[j] * xa[2]; acc[i][3] += wa[j] * xa[3];
        }
      }
    }
  }
  const int t = t0 + tx * 4;
  if (t < TLEN) {
#pragma unroll
    for (int i = 0; i < 4; ++i) {
      float4 res; res.x = acc[i][0]; res.y = acc[i][1]; res.z = acc[i][2]; res.w = acc[i][3];
      *reinterpret_cast<float4*>(
          part + ((long)(split * 4 + b) * 512 + o0 + ty * 4 + i) * TLEN + t) = res;
    }
  }
}

// ---------------- fc2 + final spike scan fused, writes d_out ----------------
__global__ __launch_bounds__(320) void fc2_spike_kernel(const float* __restrict__ x,
                                                        const float* __restrict__ w,
                                                        float* __restrict__ out) {
  __shared__ float ul[304];
  int blk = blockIdx.x;
  int b = blk / 11, o = blk % 11;
  int t = threadIdx.x;
  if (t < TLEN) {
    const float* xr = x + (long)b * 512 * TLEN + t;
    const float* wr = w + o * 512;
    float a0 = 0.f, a1 = 0.f, a2 = 0.f, a3 = 0.f;
#pragma unroll 4
    for (int i = 0; i < 512; i += 4) {
      a0 += wr[i] * xr[(long)i * TLEN];
      a1 += wr[i + 1] * xr[(long)(i + 1) * TLEN];
      a2 += wr[i + 2] * xr[(long)(i + 2) * TLEN];
      a3 += wr[i + 3] * xr[(long)(i + 3) * TLEN];
    }
    ul[t] = (a0 + a1) + (a2 + a3);
  }
  __syncthreads();
  if (t == 0) {
    float ref = 0.f;
#pragma unroll 4
    for (int c = 0; c < TLEN; ++c) {
      float v = ul[c] + ref - THETA;
      float sp = (v >= 0.f) ? 1.f : 0.f;
      ul[c] = sp;
      ref = REF_DECAY * ref - 20.0f * sp;
    }
  }
  __syncthreads();
  if (t < TLEN) out[((long)b * 11 + o) * TLEN + t] = ul[t];
}

extern "C" void kernel_launch(void* const* d_in, const int* in_sizes, int n_in,
                              void* d_out, int out_size, void* d_ws, size_t ws_size,
                              hipStream_t stream) {
  const float* input = (const float*)d_in[0];
  const float* w1    = (const float*)d_in[1];
  const float* w2    = (const float*)d_in[2];
  const float* wfc1  = (const float*)d_in[3];
  const float* wfc2  = (const float*)d_in[4];
  const float* d1    = (const float*)d_in[5];
  const float* d2    = (const float*)d_in[6];
  const float* d3    = (const float*)d_in[7];

  float* ws   = (float*)d_ws;
  float* big0 = ws;                    // 19,660,800 floats (conv outs; fc1 partials 4x614400)
  float* medA = big0 + 19660800;
  float* medB = medA + 4915200;
  float* fcA  = medB + 4915200;
  float* fcB  = fcA + 614400;
  float* eps  = fcB + 614400;

  hipLaunchKernelGGL(eps_init_kernel, dim3(1), dim3(128), 0, stream, eps);

  // L1: psp(spike(psp(pool4(input))))  -> medB = psp(S0), ready for conv1
  hipLaunchKernelGGL(pool4_kernel, dim3(600), dim3(256), 0, stream, input, medA);
  hipLaunchKernelGGL(psp_spike_psp_kernel, dim3(512), dim3(256), 0, stream, medA, medB, eps);
  // L2: spike(conv1(psp(S0)))
  hipLaunchKernelGGL(conv1_kernel, dim3(10, 32, 4), dim3(256), 0, stream, medB, w1, big0);
  hipLaunchKernelGGL(spike64_kernel, dim3(1024), dim3(64), 0, stream, big0, big0, 65536);
  // L3: psp(spike(psp(pool2(delay1(S1))))) -> medB = psp(S2), ready for conv2
  hipLaunchKernelGGL(pool2_delay_kernel, dim3(19200), dim3(256), 0, stream,
                     big0, d1, medA, 16, 16, 16, 4915200);
  hipLaunchKernelGGL(psp_spike_psp_kernel, dim3(1024), dim3(256), 0, stream, medA, medB, eps);
  // L4: spike(conv2(psp(S2)))
  hipLaunchKernelGGL(conv2_kernel, dim3(19, 16, 4), dim3(256), 0, stream, medB, w2, big0);
  hipLaunchKernelGGL(spike64_kernel, dim3(512), dim3(64), 0, stream, big0, big0, 32768);
  // L5: psp(spike(psp(pool2(delay2(S3))))) -> medB = psp(S4), ready for fc1
  hipLaunchKernelGGL(pool2_delay_kernel, dim3(9600), dim3(256), 0, stream,
                     big0, d2, medA, 32, 8, 8, 2457600);
  hipLaunchKernelGGL(psp_spike_psp_kernel, dim3(512), dim3(256), 0, stream, medA, medB, eps);
  // L6+L7 head: fc1 -> partials; reduce+spike+delay3+psp -> fcA = psp(delay3(S5))
  hipLaunchKernelGGL(fc1_kernel, dim3(5, 8, 16), dim3(256), 0, stream, medB, wfc1, big0);
  hipLaunchKernelGGL(reduce_spike_delay_psp_kernel, dim3(128), dim3(256), 0, stream,
                     big0, d3, fcA, eps);
  // L7: spike(fc2(psp(delay3(S5)))) -> d_out
  hipLaunchKernelGGL(fc2_spike_kernel, dim3(44), dim3(320), 0, stream, fcA, wfc2, (float*)d_out);
}